// Round 4
// baseline (249.791 us; speedup 1.0000x reference)
//
#include <hip/hip_runtime.h>

typedef __attribute__((ext_vector_type(8))) __bf16 bf16x8;
typedef __attribute__((ext_vector_type(4))) float f32x4;

#define DEVINL __device__ __forceinline__

constexpr int BZ = 4;
constexpr int SEQ = 1024;
constexpr int DMODEL = 1024;
constexpr int NH = 16;
constexpr int HD = 64;               // dk = dv = 64
constexpr int MSLOT = 128;
constexpr int NT = BZ * SEQ;         // 4096 tokens
constexpr int SKM = SEQ + MSLOT;     // 1152 keys per batch
constexpr int VT_LD = BZ * SKM;      // 4608: leading dim of global V^T
constexpr float SCALE_M = 11.313708498984761f;   // sqrt(128)
constexpr float SCEXP = 0.18033688011112042f;    // (1/sqrt(dk)) * log2(e), folded into Q
// workspace offsets in bf16 (ushort) elements
constexpr size_t OF_QIN  = 0;
constexpr size_t OF_KIN  = OF_QIN  + (size_t)NT * DMODEL;
constexpr size_t OF_VIN  = OF_KIN  + (size_t)NT * DMODEL;
constexpr size_t OF_WQT  = OF_VIN  + (size_t)NT * DMODEL;
constexpr size_t OF_WKT  = OF_WQT  + (size_t)DMODEL * DMODEL;
constexpr size_t OF_WVT  = OF_WKT  + (size_t)DMODEL * DMODEL;
constexpr size_t OF_WOT  = OF_WVT  + (size_t)DMODEL * DMODEL;
constexpr size_t OF_QB   = OF_WOT  + (size_t)DMODEL * DMODEL;
constexpr size_t OF_KPR  = OF_QB   + (size_t)NT * DMODEL;
constexpr size_t OF_KMEM = OF_KPR  + (size_t)NT * DMODEL;
constexpr size_t OF_VTG  = OF_KMEM + (size_t)MSLOT * DMODEL;
constexpr size_t OF_AOUT = OF_VTG  + (size_t)DMODEL * VT_LD;

DEVINL unsigned short f2bf(float f) {
  union { float f; unsigned u; } v; v.f = f;
  unsigned r = v.u + 0x7FFF + ((v.u >> 16) & 1);   // RNE
  return (unsigned short)(r >> 16);
}

#if __has_builtin(__builtin_amdgcn_cvt_pk_bf16_f32)
DEVINL unsigned pack2(float a, float b) {
  auto t = __builtin_amdgcn_cvt_pk_bf16_f32(a, b);
  unsigned r; __builtin_memcpy(&r, &t, 4); return r;
}
#else
DEVINL unsigned pack2(float a, float b) {
  return (unsigned)f2bf(a) | ((unsigned)f2bf(b) << 16);
}
#endif

#if __has_builtin(__builtin_amdgcn_exp2f)
DEVINL float fast_exp2(float x) { return __builtin_amdgcn_exp2f(x); }
#else
DEVINL float fast_exp2(float x) { return exp2f(x); }
#endif

DEVINL f32x4 mfma16(bf16x8 a, bf16x8 b, f32x4 c) {
  return __builtin_amdgcn_mfma_f32_16x16x32_bf16(a, b, c, 0, 0, 0);
}

// async global -> LDS, 16 bytes per lane (global_load_lds_dwordx4)
DEVINL void gload16(const unsigned short* gp, unsigned short* lp) {
  __builtin_amdgcn_global_load_lds(
      (const __attribute__((address_space(1))) unsigned int*)(const void*)gp,
      (__attribute__((address_space(3))) unsigned int*)(void*)lp, 16, 0, 0);
}

// ---------------- merged prep kernel ----------------
__global__ __launch_bounds__(256) void prep_all(
    const float* __restrict__ q, const float* __restrict__ k, const float* __restrict__ v,
    const float* __restrict__ W0, const float* __restrict__ W1,
    const float* __restrict__ W2, const float* __restrict__ W3,
    const float* __restrict__ mk, const float* __restrict__ mv,
    unsigned short* __restrict__ dq, unsigned short* __restrict__ dk,
    unsigned short* __restrict__ dv,
    unsigned short* __restrict__ d0, unsigned short* __restrict__ d1,
    unsigned short* __restrict__ d2, unsigned short* __restrict__ d3,
    unsigned short* __restrict__ Kmm, unsigned short* __restrict__ VtG) {
  __shared__ float t[32][65];
  const int tid = threadIdx.x;
  const int bid = blockIdx.x;
  if (bid < 6144) {
    const int tz = bid >> 11;
    const float* src = (tz == 0) ? q : (tz == 1) ? k : v;
    unsigned short* dst = (tz == 0) ? dq : (tz == 1) ? dk : dv;
    int i = ((bid & 2047) * 256 + tid) * 8;
    float4 v0 = *(const float4*)(src + i);
    float4 v1 = *(const float4*)(src + i + 4);
    union { unsigned u2[4]; uint4 v; } o;
    o.u2[0] = pack2(v0.x, v0.y); o.u2[1] = pack2(v0.z, v0.w);
    o.u2[2] = pack2(v1.x, v1.y); o.u2[3] = pack2(v1.z, v1.w);
    *(uint4*)(dst + i) = o.v;
  } else if (bid < 8192) {
    const int rel = bid - 6144;
    const int z = rel >> 9, rem = rel & 511;
    const float* src = (z == 0) ? W0 : (z == 1) ? W1 : (z == 2) ? W2 : W3;
    unsigned short* dst = (z == 0) ? d0 : (z == 1) ? d1 : (z == 2) ? d2 : d3;
    const int n0 = (rem & 31) * 32, k0 = (rem >> 5) * 64;
    {
      int c = tid & 31, rg = tid >> 5;
#pragma unroll
      for (int rr = 0; rr < 8; ++rr)
        t[c][rg * 8 + rr] = src[(size_t)(k0 + rg * 8 + rr) * DMODEL + n0 + c];
    }
    __syncthreads();
    {
      int n = tid >> 3, ck = tid & 7;
      union { unsigned short u[8]; uint4 v; } o;
#pragma unroll
      for (int j = 0; j < 8; ++j) o.u[j] = f2bf(t[n][ck * 8 + j]);
      *(uint4*)(dst + (size_t)(n0 + n) * DMODEL + k0 + ck * 8) = o.v;
    }
  } else if (bid < 8704) {
    int i = (bid - 8192) * 256 + tid;
    Kmm[i] = f2bf(mk[i] * SCALE_M);
  } else {
    const int rel = bid - 8704;
    const int j0 = (rel & 3) * 32, c0 = (rel >> 2) * 32;
    const int tx = tid & 31, ty = tid >> 5;
#pragma unroll
    for (int r = 0; r < 4; ++r)
      t[ty + r * 8][tx] = mv[(size_t)(j0 + ty + r * 8) * DMODEL + c0 + tx];
    __syncthreads();
#pragma unroll
    for (int r = 0; r < 4; ++r) {
      int c = c0 + ty + r * 8;
      unsigned short vv = f2bf(t[tx][ty + r * 8] * SCALE_M);
#pragma unroll
      for (int bb = 0; bb < BZ; ++bb)
        VtG[(size_t)c * VT_LD + bb * SKM + SEQ + j0 + tx] = vv;
    }
  }
}

// ---------------- proj GEMM: m97 shape. BM=BN=128, BK=64, 4 waves, 64x64/wave.
// Single-buffer, 2 barriers per K-step (m97-verified structure, 874-912 TF at
// 4096^3). 32 MFMA/wave/K-step amortizes the barrier drain; 768 blocks = 3/CU.
__global__ __launch_bounds__(256, 3) void proj_qkv(
    const unsigned short* __restrict__ Qin, const unsigned short* __restrict__ Kin,
    const unsigned short* __restrict__ Vin, const unsigned short* __restrict__ Wqt,
    const unsigned short* __restrict__ Wkt, const unsigned short* __restrict__ Wvt,
    const float* __restrict__ bq, const float* __restrict__ bk,
    const float* __restrict__ bv, unsigned short* __restrict__ Qbp,
    unsigned short* __restrict__ Kprp, unsigned short* __restrict__ VtG) {
  __shared__ unsigned short As0[128 * 32], As1[128 * 32];   // A tile, K-halves
  __shared__ unsigned short Bs0[128 * 32], Bs1[128 * 32];   // B tile, K-halves
  const int tid = threadIdx.x;
  const int pid = blockIdx.x >> 8;         // 0=Q 1=K 2=V
  const int idx = blockIdx.x & 255;
  const int w = tid >> 6, lane = tid & 63, quad = lane >> 4, l16 = lane & 15;
  const int wr = w >> 1, wc = w & 1;
  const int mt = idx & 31, nt = idx >> 5;  // bid%8 = m%8 (XCD L2 locality)
  f32x4 acc[4][4] = {};

  const unsigned short* Abase;
  const unsigned short* Bbase;
  if (pid == 0)      { Abase = Qin + (size_t)(mt * 128) * DMODEL; Bbase = Wqt + (size_t)(nt * 128) * DMODEL; }
  else if (pid == 1) { Abase = Kin + (size_t)(mt * 128) * DMODEL; Bbase = Wkt + (size_t)(nt * 128) * DMODEL; }
  else               { Abase = Wvt + (size_t)(nt * 128) * DMODEL; Bbase = Vin + (size_t)(mt * 128) * DMODEL; }

  const int srow = tid >> 2, sslot = tid & 3;   // 256 threads: 64 rows x 4 slots
  for (int kt = 0; kt < 16; ++kt) {
    const int k0 = kt * 64;
#pragma unroll
    for (int hb = 0; hb < 2; ++hb) {
      unsigned short* al = hb ? As1 : As0;
      unsigned short* bl = hb ? Bs1 : Bs0;
#pragma unroll
      for (int gi = 0; gi < 2; ++gi) {
        int g = gi * 256 + tid;
        int row = g >> 2, slot = g & 3;
        gload16(Abase + (size_t)row * DMODEL + k0 + hb * 32 + slot * 8, al + g * 8);
        gload16(Bbase + (size_t)row * DMODEL + k0 + hb * 32 + slot * 8, bl + g * 8);
      }
    }
    __syncthreads();
#pragma unroll
    for (int hb = 0; hb < 2; ++hb) {
      const unsigned short* al = hb ? As1 : As0;
      const unsigned short* bl = hb ? Bs1 : Bs0;
      bf16x8 af[4], bfr[4];
#pragma unroll
      for (int rb = 0; rb < 4; ++rb)
        af[rb] = *(const bf16x8*)(al + (wr * 64 + rb * 16 + l16) * 32 + quad * 8);
#pragma unroll
      for (int cb = 0; cb < 4; ++cb)
        bfr[cb] = *(const bf16x8*)(bl + (wc * 64 + cb * 16 + l16) * 32 + quad * 8);
#pragma unroll
      for (int rb = 0; rb < 4; ++rb)
#pragma unroll
        for (int cb = 0; cb < 4; ++cb)
          acc[rb][cb] = mfma16(af[rb], bfr[cb], acc[rb][cb]);
    }
    __syncthreads();
  }

  if (pid < 2) {
    const float* bias   = pid ? bk : bq;
    unsigned short* out = pid ? Kprp : Qbp;
    const float osc     = pid ? 1.0f : SCEXP;
    const int m0 = mt * 128, n0 = nt * 128;
#pragma unroll
    for (int rb = 0; rb < 4; ++rb)
#pragma unroll
      for (int cb = 0; cb < 4; ++cb)
#pragma unroll
        for (int r = 0; r < 4; ++r) {
          int row = m0 + wr * 64 + rb * 16 + quad * 4 + r;
          int col = n0 + wc * 64 + cb * 16 + l16;
          out[(size_t)row * DMODEL + col] = f2bf((acc[rb][cb][r] + bias[col]) * osc);
        }
  } else {
    const int t0 = mt * 128, n0 = nt * 128;
#pragma unroll
    for (int rb = 0; rb < 4; ++rb)
#pragma unroll
      for (int cb = 0; cb < 4; ++cb)
#pragma unroll
        for (int r = 0; r < 4; ++r) {
          int n = n0 + wr * 64 + rb * 16 + quad * 4 + r;
          int tok = t0 + wc * 64 + cb * 16 + l16;
          int col = tok + (tok >> 10) * MSLOT;
          VtG[(size_t)n * VT_LD + col] = f2bf(acc[rb][cb][r] + bv[n]);
        }
  }
}

// output GEMM: BM=64 BN=64 BK=64, 1024 blocks = 4/CU (latency-bound -> more TLP).
// idx&63 = m-tile so bid%8 = m%8 (A-tile consumers share an XCD L2 slice).
__global__ __launch_bounds__(256) void gemm_out(const unsigned short* __restrict__ A,
                                                const unsigned short* __restrict__ Wt,
                                                const float* __restrict__ bias,
                                                float* __restrict__ Cout) {
  __shared__ unsigned short A0[64 * 32], A1[64 * 32];
  __shared__ unsigned short B0[64 * 32], B1[64 * 32];
  const int tid = threadIdx.x;
  const int idx = blockIdx.x;
  const int m0 = (idx & 63) * 64, n0 = (idx >> 6) * 64;    // bid%8 = m%8
  const int w = tid >> 6, lane = tid & 63, quad = lane >> 4, l16 = lane & 15;
  const int wr = w >> 1, wc = w & 1;
  f32x4 acc[2][2] = {};
  const unsigned short* rA = A + (size_t)m0 * DMODEL;
  const unsigned short* rB = Wt + (size_t)n0 * DMODEL;
  const int srow = tid >> 2, sslot = tid & 3;
  for (int kt = 0; kt < 16; ++kt) {
    const int k0 = kt * 64;
    gload16(rA + (size_t)srow * DMODEL + k0 + sslot * 8, A0 + tid * 8);
    gload16(rA + (size_t)srow * DMODEL + k0 + 32 + sslot * 8, A1 + tid * 8);
    gload16(rB + (size_t)srow * DMODEL + k0 + sslot * 8, B0 + tid * 8);
    gload16(rB + (size_t)srow * DMODEL + k0 + 32 + sslot * 8, B1 + tid * 8);
    __syncthreads();
#pragma unroll
    for (int hb = 0; hb < 2; ++hb) {
      const unsigned short* al = hb ? A1 : A0;
      const unsigned short* bl = hb ? B1 : B0;
      bf16x8 af[2], bfr[2];
#pragma unroll
      for (int rb = 0; rb < 2; ++rb)
        af[rb] = *(const bf16x8*)(al + (wr * 32 + rb * 16 + l16) * 32 + quad * 8);
#pragma unroll
      for (int cb = 0; cb < 2; ++cb)
        bfr[cb] = *(const bf16x8*)(bl + (wc * 32 + cb * 16 + l16) * 32 + quad * 8);
#pragma unroll
      for (int rb = 0; rb < 2; ++rb)
#pragma unroll
        for (int cb = 0; cb < 2; ++cb)
          acc[rb][cb] = mfma16(af[rb], bfr[cb], acc[rb][cb]);
    }
    __syncthreads();
  }
#pragma unroll
  for (int rb = 0; rb < 2; ++rb)
#pragma unroll
    for (int cb = 0; cb < 2; ++cb)
#pragma unroll
      for (int r = 0; r < 4; ++r) {
        int row = m0 + wr * 32 + rb * 16 + quad * 4 + r;
        int col = n0 + wc * 32 + cb * 16 + l16;
        Cout[(size_t)row * DMODEL + col] = acc[rb][cb][r] + bias[col];
      }
}

// ---------------- flash attention v6 ----------------
// 64 q/block, bid = qb*64 + bh (all 16 qb-blocks of a bh share an XCD:
// bid%8 == bh%8). K staged in LDS (gload_lds, pre-swizzled source).
// NEW (R4): V is NOT staged in LDS. Per (b,h) V = 147 KB; K+V ~2.4 MB/XCD
// -> L2-resident (m169: LDS-staging L2-fit data is pure overhead). V-operand
// fragments are read straight from global VtG into registers, double-buffered
// (vrA/vrB) across a pair-unrolled tile loop, prefetched one full tile ahead.
// Cuts ~41% of per-tile LDS traffic (32 ds_read_b128 + 8 KB staging / tile).
// LDS 40->24 KB; VGPR ~116 (still 4 waves/SIMD).
__global__ __launch_bounds__(256) void attn_kernel(const unsigned short* __restrict__ Qb,
                                                   const unsigned short* __restrict__ Kproj,
                                                   const unsigned short* __restrict__ Kmem,
                                                   const unsigned short* __restrict__ VtG,
                                                   unsigned short* __restrict__ Aout) {
  __shared__ unsigned short Ks[2][64 * 64];
  __shared__ unsigned short Pl[4 * 16 * 64];    // per-wave P[q][key], swizzled
  const int tid = threadIdx.x;
  const int bh = blockIdx.x & 63, qb = blockIdx.x >> 6;
  const int b = bh & 3, h = bh >> 2;
  const int w = tid >> 6, lane = tid & 63, quad = lane >> 4, l16 = lane & 15;
  const int token0 = b * SEQ + qb * 64 + w * 16;
  unsigned short* Pw = Pl + w * 16 * 64;
  const int lx = l16 & 7;                       // row&7 for swizzle (rows differ by 16)

  // K staging via gload_lds: wave w stages chunks 2w,2w+1 (1 KiB each).
  const int ck0 = 2 * w, ck1 = 2 * w + 1;
  const int lrow = lane >> 3;
  const int lslot = (lane & 7) ^ lrow;          // pre-swizzled source slot
  const size_t ksrc0 = (size_t)(8 * ck0 + lrow) * DMODEL + lslot * 8;
  const size_t ksrc1 = (size_t)(8 * ck1 + lrow) * DMODEL + lslot * 8;
  const int ldst0 = ck0 * 512 + lane * 8;       // ushort offsets, lane-linear
  const int ldst1 = ck1 * 512 + lane * 8;

  auto kbase = [&](int tile) -> const unsigned short* {
    return (tile < 16) ? Kproj + (size_t)(b * SEQ + tile * 64) * DMODEL + h * HD
                       : Kmem + (size_t)((tile - 16) * 64) * DMODEL + h * HD;
  };
  auto vbase = [&](int tile) -> const unsigned short* {
    int c0 = (tile < 16) ? b * SKM + tile * 64 : b * SKM + SEQ + (tile - 16) * 64;
    return VtG + (size_t)(h * HD) * VT_LD + c0;
  };

  auto stageK = [&](int buf, int tile) {
    const unsigned short* kp = kbase(tile);
    gload16(kp + ksrc0, Ks[buf] + ldst0);
    gload16(kp + ksrc1, Ks[buf] + ldst1);
  };
  // V fragment load: vr[t2][c2] = V^T[dv=c2*16+l16][key chunk (t2*4+quad)*8]
  auto vload = [&](bf16x8 (&vr)[2][4], int tile) {
    const unsigned short* vp = vbase(tile);
#pragma unroll
    for (int t2 = 0; t2 < 2; ++t2)
#pragma unroll
      for (int c2 = 0; c2 < 4; ++c2)
        vr[t2][c2] = *(const bf16x8*)(vp + (size_t)(c2 * 16 + l16) * VT_LD +
                                      (t2 * 4 + quad) * 8);
  };

  bf16x8 qf[2];   // B-operand: Q[n=l16][k = quad*8+j (+32t)] (pre-scaled by SCEXP)
#pragma unroll
  for (int t = 0; t < 2; ++t)
    qf[t] = *(const bf16x8*)(Qb + (size_t)(token0 + l16) * DMODEL + h * HD + t * 32 + quad * 8);

  bf16x8 ones;
  {
    union { unsigned short u[8]; bf16x8 v; } one8;
#pragma unroll
    for (int i = 0; i < 8; ++i) one8.u[i] = 0x3F80;   // bf16 1.0
    ones = one8.v;
  }

  f32x4 O[4] = {};
  f32x4 Lacc = {};

  // one full tile of compute: QK^T from Ks[buf], softmax -> Pw, PV with vr.
  auto tilecomp = [&](const unsigned short* Kbuf, bf16x8 (&vr)[2][4]) {
    f32x4 sc[4] = {};
    __builtin_amdgcn_s_setprio(1);
#pragma unroll
    for (int c = 0; c < 4; ++c)
#pragma unroll
      for (int t = 0; t < 2; ++t) {
        bf16x8 kb = *(const bf16x8*)(Kbuf + (c * 16 + l16) * 64 +
                                     ((t * 4 + quad) ^ lx) * 8);
        sc[c] = mfma16(kb, qf[t], sc[c]);
      }
    __builtin_amdgcn_s_setprio(0);

#pragma unroll
    for (int c = 0; c < 4; ++c) {
      float p0 = fast_exp2(sc[c][0]);
      float p1 = fast_exp2(sc[c][1]);
      float p2 = fast_exp2(sc[c][2]);
      float p3 = fast_exp2(sc[c][3]);
      union { unsigned u[2]; } pk;
      pk.u[0] = pack2(p0, p1);
      pk.u[1] = pack2(p2, p3);
      *(uint2*)(Pw + l16 * 64 + ((2 * c + (quad >> 1)) ^ lx) * 8 + (quad & 1) * 4) =
          *(uint2*)pk.u;
    }
    __builtin_amdgcn_wave_barrier();   // order DS write -> DS read (wave-local)

    __builtin_amdgcn_s_setprio(1);
#pragma unroll
    for (int t2 = 0; t2 < 2; ++t2) {
      bf16x8 pa = *(const bf16x8*)(Pw + l16 * 64 + ((t2 * 4 + quad) ^ lx) * 8);
      Lacc = mfma16(pa, ones, Lacc);   // row sums of P: lsum[q=quad*4+r]
#pragma unroll
      for (int c2 = 0; c2 < 4; ++c2)
        O[c2] = mfma16(pa, vr[t2][c2], O[c2]);
    }
    __builtin_amdgcn_s_setprio(0);
  };

  bf16x8 vrA[2][4], vrB[2][4];
  vload(vrA, 0);
  stageK(0, 0);
  __syncthreads();   // drains vmcnt(0): K tile 0 resident, vrA in flight->waited on use

  for (int p = 0; p < 9; ++p) {
    // tile 2p (Ks[0], vrA); prefetch tile 2p+1 into Ks[1]/vrB
    vload(vrB, 2 * p + 1);
    stageK(1, 2 * p + 1);
    tilecomp(Ks[0], vrA);
    __syncthreads();   // Ks[1] + vrB complete; Ks[0] free
    // tile 2p+1 (Ks[1], vrB); prefetch tile 2p+2 into Ks[0]/vrA
    if (p < 8) {
      vload(vrA, 2 * p + 2);
      stageK(0, 2 * p + 2);
    }
    tilecomp(Ks[1], vrB);
    __syncthreads();   // Ks[0] + vrA complete; Ks[1] free
  }

#pragma unroll
  for (int r = 0; r < 4; ++r) {
    float inv = 1.0f / Lacc[r];
#pragma unroll
    for (int c2 = 0; c2 < 4; ++c2)
      Aout[(size_t)(token0 + quad * 4 + r) * DMODEL + h * HD + c2 * 16 + l16] =
          f2bf(O[c2][r] * inv);
  }
}

// ---------------- launch ----------------
extern "C" void kernel_launch(void* const* d_in, const int* in_sizes, int n_in,
                              void* d_out, int out_size, void* d_ws, size_t ws_size,
                              hipStream_t stream) {
  const float* queries = (const float*)d_in[0];
  const float* keys    = (const float*)d_in[1];
  const float* values  = (const float*)d_in[2];
  const float* Wq = (const float*)d_in[3];
  const float* bq = (const float*)d_in[4];
  const float* Wk = (const float*)d_in[5];
  const float* bk = (const float*)d_in[6];
  const float* Wv = (const float*)d_in[7];
  const float* bv = (const float*)d_in[8];
  const float* Wo = (const float*)d_in[9];
  const float* bo = (const float*)d_in[10];
  const float* mk = (const float*)d_in[11];
  const float* mv = (const float*)d_in[12];

  unsigned short* ws = (unsigned short*)d_ws;
  unsigned short* Qin  = ws + OF_QIN;
  unsigned short* Kin  = ws + OF_KIN;
  unsigned short* Vin  = ws + OF_VIN;
  unsigned short* Wqt  = ws + OF_WQT;
  unsigned short* Wkt  = ws + OF_WKT;
  unsigned short* Wvt  = ws + OF_WVT;
  unsigned short* Wot  = ws + OF_WOT;
  unsigned short* Qbp  = ws + OF_QB;
  unsigned short* Kprp = ws + OF_KPR;
  unsigned short* Kmm  = ws + OF_KMEM;
  unsigned short* VtGp = ws + OF_VTG;
  unsigned short* Aoutp = ws + OF_AOUT;

  prep_all<<<8832, 256, 0, stream>>>(queries, keys, values, Wq, Wk, Wv, Wo, mk, mv,
                                     Qin, Kin, Vin, Wqt, Wkt, Wvt, Wot, Kmm, VtGp);

  proj_qkv<<<768, 256, 0, stream>>>(Qin, Kin, Vin, Wqt, Wkt, Wvt, bq, bk, bv,
                                    Qbp, Kprp, VtGp);

  attn_kernel<<<1024, 256, 0, stream>>>(Qbp, Kprp, Kmm, VtGp, Aoutp);

  gemm_out<<<1024, 256, 0, stream>>>(Aoutp, Wot, bo, (float*)d_out);
}

// Round 5
// 201.767 us; speedup vs baseline: 1.2380x; 1.2380x over previous
//
#include <hip/hip_runtime.h>

typedef __attribute__((ext_vector_type(8))) __bf16 bf16x8;
typedef __attribute__((ext_vector_type(4))) float f32x4;

#define DEVINL __device__ __forceinline__

constexpr int BZ = 4;
constexpr int SEQ = 1024;
constexpr int DMODEL = 1024;
constexpr int NH = 16;
constexpr int HD = 64;               // dk = dv = 64
constexpr int MSLOT = 128;
constexpr int NT = BZ * SEQ;         // 4096 tokens
constexpr int SKM = SEQ + MSLOT;     // 1152 keys per batch
constexpr int VT_LD = BZ * SKM;      // 4608: leading dim of global V^T
constexpr float SCALE_M = 11.313708498984761f;   // sqrt(128)
constexpr float SCEXP = 0.18033688011112042f;    // (1/sqrt(dk)) * log2(e), folded into Q
// workspace offsets in bf16 (ushort) elements
constexpr size_t OF_QIN  = 0;
constexpr size_t OF_KIN  = OF_QIN  + (size_t)NT * DMODEL;
constexpr size_t OF_VIN  = OF_KIN  + (size_t)NT * DMODEL;
constexpr size_t OF_WQT  = OF_VIN  + (size_t)NT * DMODEL;
constexpr size_t OF_WKT  = OF_WQT  + (size_t)DMODEL * DMODEL;
constexpr size_t OF_WVT  = OF_WKT  + (size_t)DMODEL * DMODEL;
constexpr size_t OF_WOT  = OF_WVT  + (size_t)DMODEL * DMODEL;
constexpr size_t OF_QB   = OF_WOT  + (size_t)DMODEL * DMODEL;
constexpr size_t OF_KPR  = OF_QB   + (size_t)NT * DMODEL;
constexpr size_t OF_KMEM = OF_KPR  + (size_t)NT * DMODEL;
constexpr size_t OF_VTG  = OF_KMEM + (size_t)MSLOT * DMODEL;
constexpr size_t OF_AOUT = OF_VTG  + (size_t)DMODEL * VT_LD;

DEVINL unsigned short f2bf(float f) {
  union { float f; unsigned u; } v; v.f = f;
  unsigned r = v.u + 0x7FFF + ((v.u >> 16) & 1);   // RNE
  return (unsigned short)(r >> 16);
}

#if __has_builtin(__builtin_amdgcn_cvt_pk_bf16_f32)
DEVINL unsigned pack2(float a, float b) {
  auto t = __builtin_amdgcn_cvt_pk_bf16_f32(a, b);
  unsigned r; __builtin_memcpy(&r, &t, 4); return r;
}
#else
DEVINL unsigned pack2(float a, float b) {
  return (unsigned)f2bf(a) | ((unsigned)f2bf(b) << 16);
}
#endif

#if __has_builtin(__builtin_amdgcn_exp2f)
DEVINL float fast_exp2(float x) { return __builtin_amdgcn_exp2f(x); }
#else
DEVINL float fast_exp2(float x) { return exp2f(x); }
#endif

DEVINL f32x4 mfma16(bf16x8 a, bf16x8 b, f32x4 c) {
  return __builtin_amdgcn_mfma_f32_16x16x32_bf16(a, b, c, 0, 0, 0);
}

// async global -> LDS, 16 bytes per lane (global_load_lds_dwordx4)
DEVINL void gload16(const unsigned short* gp, unsigned short* lp) {
  __builtin_amdgcn_global_load_lds(
      (const __attribute__((address_space(1))) unsigned int*)(const void*)gp,
      (__attribute__((address_space(3))) unsigned int*)(void*)lp, 16, 0, 0);
}

// ---------------- merged prep kernel ----------------
__global__ __launch_bounds__(256) void prep_all(
    const float* __restrict__ q, const float* __restrict__ k, const float* __restrict__ v,
    const float* __restrict__ W0, const float* __restrict__ W1,
    const float* __restrict__ W2, const float* __restrict__ W3,
    const float* __restrict__ mk, const float* __restrict__ mv,
    unsigned short* __restrict__ dq, unsigned short* __restrict__ dk,
    unsigned short* __restrict__ dv,
    unsigned short* __restrict__ d0, unsigned short* __restrict__ d1,
    unsigned short* __restrict__ d2, unsigned short* __restrict__ d3,
    unsigned short* __restrict__ Kmm, unsigned short* __restrict__ VtG) {
  __shared__ float t[32][65];
  const int tid = threadIdx.x;
  const int bid = blockIdx.x;
  if (bid < 6144) {
    const int tz = bid >> 11;
    const float* src = (tz == 0) ? q : (tz == 1) ? k : v;
    unsigned short* dst = (tz == 0) ? dq : (tz == 1) ? dk : dv;
    int i = ((bid & 2047) * 256 + tid) * 8;
    float4 v0 = *(const float4*)(src + i);
    float4 v1 = *(const float4*)(src + i + 4);
    union { unsigned u2[4]; uint4 v; } o;
    o.u2[0] = pack2(v0.x, v0.y); o.u2[1] = pack2(v0.z, v0.w);
    o.u2[2] = pack2(v1.x, v1.y); o.u2[3] = pack2(v1.z, v1.w);
    *(uint4*)(dst + i) = o.v;
  } else if (bid < 8192) {
    const int rel = bid - 6144;
    const int z = rel >> 9, rem = rel & 511;
    const float* src = (z == 0) ? W0 : (z == 1) ? W1 : (z == 2) ? W2 : W3;
    unsigned short* dst = (z == 0) ? d0 : (z == 1) ? d1 : (z == 2) ? d2 : d3;
    const int n0 = (rem & 31) * 32, k0 = (rem >> 5) * 64;
    {
      int c = tid & 31, rg = tid >> 5;
#pragma unroll
      for (int rr = 0; rr < 8; ++rr)
        t[c][rg * 8 + rr] = src[(size_t)(k0 + rg * 8 + rr) * DMODEL + n0 + c];
    }
    __syncthreads();
    {
      int n = tid >> 3, ck = tid & 7;
      union { unsigned short u[8]; uint4 v; } o;
#pragma unroll
      for (int j = 0; j < 8; ++j) o.u[j] = f2bf(t[n][ck * 8 + j]);
      *(uint4*)(dst + (size_t)(n0 + n) * DMODEL + k0 + ck * 8) = o.v;
    }
  } else if (bid < 8704) {
    int i = (bid - 8192) * 256 + tid;
    Kmm[i] = f2bf(mk[i] * SCALE_M);
  } else {
    const int rel = bid - 8704;
    const int j0 = (rel & 3) * 32, c0 = (rel >> 2) * 32;
    const int tx = tid & 31, ty = tid >> 5;
#pragma unroll
    for (int r = 0; r < 4; ++r)
      t[ty + r * 8][tx] = mv[(size_t)(j0 + ty + r * 8) * DMODEL + c0 + tx];
    __syncthreads();
#pragma unroll
    for (int r = 0; r < 4; ++r) {
      int c = c0 + ty + r * 8;
      unsigned short vv = f2bf(t[tx][ty + r * 8] * SCALE_M);
#pragma unroll
      for (int bb = 0; bb < BZ; ++bb)
        VtG[(size_t)c * VT_LD + bb * SKM + SEQ + j0 + tx] = vv;
    }
  }
}

// ---------------- proj GEMM: m97 shape. BM=BN=128, BK=64, 4 waves, 64x64/wave.
// Single-buffer, 2 barriers per K-step (m97-verified structure, 874-912 TF at
// 4096^3). 32 MFMA/wave/K-step amortizes the barrier drain; 768 blocks = 3/CU.
__global__ __launch_bounds__(256, 3) void proj_qkv(
    const unsigned short* __restrict__ Qin, const unsigned short* __restrict__ Kin,
    const unsigned short* __restrict__ Vin, const unsigned short* __restrict__ Wqt,
    const unsigned short* __restrict__ Wkt, const unsigned short* __restrict__ Wvt,
    const float* __restrict__ bq, const float* __restrict__ bk,
    const float* __restrict__ bv, unsigned short* __restrict__ Qbp,
    unsigned short* __restrict__ Kprp, unsigned short* __restrict__ VtG) {
  __shared__ unsigned short As0[128 * 32], As1[128 * 32];   // A tile, K-halves
  __shared__ unsigned short Bs0[128 * 32], Bs1[128 * 32];   // B tile, K-halves
  const int tid = threadIdx.x;
  const int pid = blockIdx.x >> 8;         // 0=Q 1=K 2=V
  const int idx = blockIdx.x & 255;
  const int w = tid >> 6, lane = tid & 63, quad = lane >> 4, l16 = lane & 15;
  const int wr = w >> 1, wc = w & 1;
  const int mt = idx & 31, nt = idx >> 5;  // bid%8 = m%8 (XCD L2 locality)
  f32x4 acc[4][4] = {};

  const unsigned short* Abase;
  const unsigned short* Bbase;
  if (pid == 0)      { Abase = Qin + (size_t)(mt * 128) * DMODEL; Bbase = Wqt + (size_t)(nt * 128) * DMODEL; }
  else if (pid == 1) { Abase = Kin + (size_t)(mt * 128) * DMODEL; Bbase = Wkt + (size_t)(nt * 128) * DMODEL; }
  else               { Abase = Wvt + (size_t)(nt * 128) * DMODEL; Bbase = Vin + (size_t)(mt * 128) * DMODEL; }

  for (int kt = 0; kt < 16; ++kt) {
    const int k0 = kt * 64;
#pragma unroll
    for (int hb = 0; hb < 2; ++hb) {
      unsigned short* al = hb ? As1 : As0;
      unsigned short* bl = hb ? Bs1 : Bs0;
#pragma unroll
      for (int gi = 0; gi < 2; ++gi) {
        int g = gi * 256 + tid;
        int row = g >> 2, slot = g & 3;
        gload16(Abase + (size_t)row * DMODEL + k0 + hb * 32 + slot * 8, al + g * 8);
        gload16(Bbase + (size_t)row * DMODEL + k0 + hb * 32 + slot * 8, bl + g * 8);
      }
    }
    __syncthreads();
#pragma unroll
    for (int hb = 0; hb < 2; ++hb) {
      const unsigned short* al = hb ? As1 : As0;
      const unsigned short* bl = hb ? Bs1 : Bs0;
      bf16x8 af[4], bfr[4];
#pragma unroll
      for (int rb = 0; rb < 4; ++rb)
        af[rb] = *(const bf16x8*)(al + (wr * 64 + rb * 16 + l16) * 32 + quad * 8);
#pragma unroll
      for (int cb = 0; cb < 4; ++cb)
        bfr[cb] = *(const bf16x8*)(bl + (wc * 64 + cb * 16 + l16) * 32 + quad * 8);
#pragma unroll
      for (int rb = 0; rb < 4; ++rb)
#pragma unroll
        for (int cb = 0; cb < 4; ++cb)
          acc[rb][cb] = mfma16(af[rb], bfr[cb], acc[rb][cb]);
    }
    __syncthreads();
  }

  if (pid < 2) {
    const float* bias   = pid ? bk : bq;
    unsigned short* out = pid ? Kprp : Qbp;
    const float osc     = pid ? 1.0f : SCEXP;
    const int m0 = mt * 128, n0 = nt * 128;
#pragma unroll
    for (int rb = 0; rb < 4; ++rb)
#pragma unroll
      for (int cb = 0; cb < 4; ++cb)
#pragma unroll
        for (int r = 0; r < 4; ++r) {
          int row = m0 + wr * 64 + rb * 16 + quad * 4 + r;
          int col = n0 + wc * 64 + cb * 16 + l16;
          out[(size_t)row * DMODEL + col] = f2bf((acc[rb][cb][r] + bias[col]) * osc);
        }
  } else {
    const int t0 = mt * 128, n0 = nt * 128;
#pragma unroll
    for (int rb = 0; rb < 4; ++rb)
#pragma unroll
      for (int cb = 0; cb < 4; ++cb)
#pragma unroll
        for (int r = 0; r < 4; ++r) {
          int n = n0 + wr * 64 + rb * 16 + quad * 4 + r;
          int tok = t0 + wc * 64 + cb * 16 + l16;
          int col = tok + (tok >> 10) * MSLOT;
          VtG[(size_t)n * VT_LD + col] = f2bf(acc[rb][cb][r] + bv[n]);
        }
  }
}

// output GEMM: BM=64 BN=64 BK=64, 1024 blocks = 4/CU (latency-bound -> more TLP).
// idx&63 = m-tile so bid%8 = m%8 (A-tile consumers share an XCD L2 slice).
__global__ __launch_bounds__(256) void gemm_out(const unsigned short* __restrict__ A,
                                                const unsigned short* __restrict__ Wt,
                                                const float* __restrict__ bias,
                                                float* __restrict__ Cout) {
  __shared__ unsigned short A0[64 * 32], A1[64 * 32];
  __shared__ unsigned short B0[64 * 32], B1[64 * 32];
  const int tid = threadIdx.x;
  const int idx = blockIdx.x;
  const int m0 = (idx & 63) * 64, n0 = (idx >> 6) * 64;    // bid%8 = m%8
  const int w = tid >> 6, lane = tid & 63, quad = lane >> 4, l16 = lane & 15;
  const int wr = w >> 1, wc = w & 1;
  f32x4 acc[2][2] = {};
  const unsigned short* rA = A + (size_t)m0 * DMODEL;
  const unsigned short* rB = Wt + (size_t)n0 * DMODEL;
  const int srow = tid >> 2, sslot = tid & 3;
  for (int kt = 0; kt < 16; ++kt) {
    const int k0 = kt * 64;
    gload16(rA + (size_t)srow * DMODEL + k0 + sslot * 8, A0 + tid * 8);
    gload16(rA + (size_t)srow * DMODEL + k0 + 32 + sslot * 8, A1 + tid * 8);
    gload16(rB + (size_t)srow * DMODEL + k0 + sslot * 8, B0 + tid * 8);
    gload16(rB + (size_t)srow * DMODEL + k0 + 32 + sslot * 8, B1 + tid * 8);
    __syncthreads();
#pragma unroll
    for (int hb = 0; hb < 2; ++hb) {
      const unsigned short* al = hb ? A1 : A0;
      const unsigned short* bl = hb ? B1 : B0;
      bf16x8 af[2], bfr[2];
#pragma unroll
      for (int rb = 0; rb < 2; ++rb)
        af[rb] = *(const bf16x8*)(al + (wr * 32 + rb * 16 + l16) * 32 + quad * 8);
#pragma unroll
      for (int cb = 0; cb < 2; ++cb)
        bfr[cb] = *(const bf16x8*)(bl + (wc * 32 + cb * 16 + l16) * 32 + quad * 8);
#pragma unroll
      for (int rb = 0; rb < 2; ++rb)
#pragma unroll
        for (int cb = 0; cb < 2; ++cb)
          acc[rb][cb] = mfma16(af[rb], bfr[cb], acc[rb][cb]);
    }
    __syncthreads();
  }
#pragma unroll
  for (int rb = 0; rb < 2; ++rb)
#pragma unroll
    for (int cb = 0; cb < 2; ++cb)
#pragma unroll
      for (int r = 0; r < 4; ++r) {
        int row = m0 + wr * 32 + rb * 16 + quad * 4 + r;
        int col = n0 + wc * 32 + cb * 16 + l16;
        Cout[(size_t)row * DMODEL + col] = acc[rb][cb][r] + bias[col];
      }
}

// ---------------- flash attention v7 ----------------
// R5: 32 q per WAVE (two 16-q groups), 128 q per block, 512 blocks.
// Each K/V LDS fragment read now feeds TWO MFMAs (one per q-group), cutting
// per-CU LDS-bank traffic ~42% (R3 analysis: attn is LDS-BW-bound at ~75-85%,
// 6.9 MB/CU; this drops it to ~4.0 MB/CU). MFMA/exp2 totals unchanged.
// Barrier/prefetch schedule identical to verified R3. 48 KB LDS, 2 blocks/CU
// = 2 waves/SIMD (VGPR budget 256 -> doubled accumulators are safe).
// bid = qb*64 + bh keeps bid%8 == bh%8 (K/V co-located per XCD L2).
__global__ __launch_bounds__(256) void attn_kernel(const unsigned short* __restrict__ Qb,
                                                   const unsigned short* __restrict__ Kproj,
                                                   const unsigned short* __restrict__ Kmem,
                                                   const unsigned short* __restrict__ VtG,
                                                   unsigned short* __restrict__ Aout) {
  __shared__ unsigned short Ks[2][64 * 64];
  __shared__ unsigned short Vs[2][64 * 64];
  __shared__ unsigned short Pl[4 * 2 * 16 * 64];   // per-wave, per-group P[q][key]
  const int tid = threadIdx.x;
  const int bh = blockIdx.x & 63, qb = blockIdx.x >> 6;   // qb in 0..7
  const int b = bh & 3, h = bh >> 2;
  const int w = tid >> 6, lane = tid & 63, quad = lane >> 4, l16 = lane & 15;
  const int token0 = b * SEQ + qb * 128 + w * 32;  // wave owns q [token0, token0+32)
  unsigned short* Pw = Pl + w * 2048;              // two 1024-ushort groups
  const int lx = l16 & 7;                          // swizzle (rows differ by 16)

  // K/V staging via gload_lds: wave w stages chunks 2w,2w+1 (1 KiB each).
  const int ck0 = 2 * w, ck1 = 2 * w + 1;
  const int lrow = lane >> 3;
  const int lslot = (lane & 7) ^ lrow;             // pre-swizzled source slot
  const size_t ksrc0 = (size_t)(8 * ck0 + lrow) * DMODEL + lslot * 8;
  const size_t ksrc1 = (size_t)(8 * ck1 + lrow) * DMODEL + lslot * 8;
  const size_t vsrc0 = (size_t)(8 * ck0 + lrow) * VT_LD + lslot * 8;
  const size_t vsrc1 = (size_t)(8 * ck1 + lrow) * VT_LD + lslot * 8;
  const int ldst0 = ck0 * 512 + lane * 8;          // ushort offsets, lane-linear
  const int ldst1 = ck1 * 512 + lane * 8;

  auto kbase = [&](int tile) -> const unsigned short* {
    return (tile < 16) ? Kproj + (size_t)(b * SEQ + tile * 64) * DMODEL + h * HD
                       : Kmem + (size_t)((tile - 16) * 64) * DMODEL + h * HD;
  };
  auto vbase = [&](int tile) -> const unsigned short* {
    int c0 = (tile < 16) ? b * SKM + tile * 64 : b * SKM + SEQ + (tile - 16) * 64;
    return VtG + (size_t)(h * HD) * VT_LD + c0;
  };

  auto stage = [&](int buf, int tile) {
    const unsigned short* kp = kbase(tile);
    const unsigned short* vp = vbase(tile);
    gload16(kp + ksrc0, Ks[buf] + ldst0);
    gload16(kp + ksrc1, Ks[buf] + ldst1);
    gload16(vp + vsrc0, Vs[buf] + ldst0);
    gload16(vp + vsrc1, Vs[buf] + ldst1);
  };

  // Q fragments for both groups (pre-scaled by SCEXP)
  bf16x8 qf[2][2];   // [group][khalf]: Q[n=l16 (+16g)][k=quad*8+j (+32t)]
#pragma unroll
  for (int g = 0; g < 2; ++g)
#pragma unroll
    for (int t = 0; t < 2; ++t)
      qf[g][t] = *(const bf16x8*)(Qb + (size_t)(token0 + g * 16 + l16) * DMODEL +
                                  h * HD + t * 32 + quad * 8);

  bf16x8 ones;
  {
    union { unsigned short u[8]; bf16x8 v; } one8;
#pragma unroll
    for (int i = 0; i < 8; ++i) one8.u[i] = 0x3F80;   // bf16 1.0
    ones = one8.v;
  }

  f32x4 O0[4] = {}, O1[4] = {};
  f32x4 Lacc0 = {}, Lacc1 = {};

  // one tile: QK^T both groups (shared kb reads) -> softmax -> PV (shared vb).
  auto tilecomp = [&](const unsigned short* Kbuf, const unsigned short* Vbuf) {
    f32x4 sc0[4] = {}, sc1[4] = {};
    __builtin_amdgcn_s_setprio(1);
#pragma unroll
    for (int c = 0; c < 4; ++c)
#pragma unroll
      for (int t = 0; t < 2; ++t) {
        bf16x8 kb = *(const bf16x8*)(Kbuf + (c * 16 + l16) * 64 +
                                     ((t * 4 + quad) ^ lx) * 8);
        sc0[c] = mfma16(kb, qf[0][t], sc0[c]);
        sc1[c] = mfma16(kb, qf[1][t], sc1[c]);
      }
    __builtin_amdgcn_s_setprio(0);

#pragma unroll
    for (int g = 0; g < 2; ++g) {
#pragma unroll
      for (int c = 0; c < 4; ++c) {
        const f32x4& s = g ? sc1[c] : sc0[c];
        float p0 = fast_exp2(s[0]);
        float p1 = fast_exp2(s[1]);
        float p2 = fast_exp2(s[2]);
        float p3 = fast_exp2(s[3]);
        union { unsigned u[2]; } pk;
        pk.u[0] = pack2(p0, p1);
        pk.u[1] = pack2(p2, p3);
        *(uint2*)(Pw + g * 1024 + l16 * 64 +
                  ((2 * c + (quad >> 1)) ^ lx) * 8 + (quad & 1) * 4) = *(uint2*)pk.u;
      }
    }
    __builtin_amdgcn_wave_barrier();   // order DS write -> DS read (wave-local)

    __builtin_amdgcn_s_setprio(1);
#pragma unroll
    for (int t2 = 0; t2 < 2; ++t2) {
      bf16x8 pa0 = *(const bf16x8*)(Pw + l16 * 64 + ((t2 * 4 + quad) ^ lx) * 8);
      bf16x8 pa1 = *(const bf16x8*)(Pw + 1024 + l16 * 64 + ((t2 * 4 + quad) ^ lx) * 8);
      Lacc0 = mfma16(pa0, ones, Lacc0);
      Lacc1 = mfma16(pa1, ones, Lacc1);
#pragma unroll
      for (int c2 = 0; c2 < 4; ++c2) {
        bf16x8 vb = *(const bf16x8*)(Vbuf + (c2 * 16 + l16) * 64 +
                                     ((t2 * 4 + quad) ^ lx) * 8);
        O0[c2] = mfma16(pa0, vb, O0[c2]);
        O1[c2] = mfma16(pa1, vb, O1[c2]);
      }
    }
    __builtin_amdgcn_s_setprio(0);
  };

  stage(0, 0);
  __syncthreads();   // drains vmcnt(0): tile 0 resident

  for (int p = 0; p < 9; ++p) {
    stage(1, 2 * p + 1);
    tilecomp(Ks[0], Vs[0]);
    __syncthreads();   // tile 2p+1 resident; buf 0 free
    if (p < 8) stage(0, 2 * p + 2);
    tilecomp(Ks[1], Vs[1]);
    __syncthreads();   // tile 2p+2 resident; buf 1 free
  }

#pragma unroll
  for (int r = 0; r < 4; ++r) {
    float inv0 = 1.0f / Lacc0[r];
    float inv1 = 1.0f / Lacc1[r];
#pragma unroll
    for (int c2 = 0; c2 < 4; ++c2) {
      Aout[(size_t)(token0 + quad * 4 + r) * DMODEL + h * HD + c2 * 16 + l16] =
          f2bf(O0[c2][r] * inv0);
      Aout[(size_t)(token0 + 16 + quad * 4 + r) * DMODEL + h * HD + c2 * 16 + l16] =
          f2bf(O1[c2][r] * inv1);
    }
  }
}

// ---------------- launch ----------------
extern "C" void kernel_launch(void* const* d_in, const int* in_sizes, int n_in,
                              void* d_out, int out_size, void* d_ws, size_t ws_size,
                              hipStream_t stream) {
  const float* queries = (const float*)d_in[0];
  const float* keys    = (const float*)d_in[1];
  const float* values  = (const float*)d_in[2];
  const float* Wq = (const float*)d_in[3];
  const float* bq = (const float*)d_in[4];
  const float* Wk = (const float*)d_in[5];
  const float* bk = (const float*)d_in[6];
  const float* Wv = (const float*)d_in[7];
  const float* bv = (const float*)d_in[8];
  const float* Wo = (const float*)d_in[9];
  const float* bo = (const float*)d_in[10];
  const float* mk = (const float*)d_in[11];
  const float* mv = (const float*)d_in[12];

  unsigned short* ws = (unsigned short*)d_ws;
  unsigned short* Qin  = ws + OF_QIN;
  unsigned short* Kin  = ws + OF_KIN;
  unsigned short* Vin  = ws + OF_VIN;
  unsigned short* Wqt  = ws + OF_WQT;
  unsigned short* Wkt  = ws + OF_WKT;
  unsigned short* Wvt  = ws + OF_WVT;
  unsigned short* Wot  = ws + OF_WOT;
  unsigned short* Qbp  = ws + OF_QB;
  unsigned short* Kprp = ws + OF_KPR;
  unsigned short* Kmm  = ws + OF_KMEM;
  unsigned short* VtGp = ws + OF_VTG;
  unsigned short* Aoutp = ws + OF_AOUT;

  prep_all<<<8832, 256, 0, stream>>>(queries, keys, values, Wq, Wk, Wv, Wo, mk, mv,
                                     Qin, Kin, Vin, Wqt, Wkt, Wvt, Wot, Kmm, VtGp);

  proj_qkv<<<768, 256, 0, stream>>>(Qin, Kin, Vin, Wqt, Wkt, Wvt, bq, bk, bv,
                                    Qbp, Kprp, VtGp);

  attn_kernel<<<512, 256, 0, stream>>>(Qbp, Kprp, Kmm, VtGp, Aoutp);

  gemm_out<<<1024, 256, 0, stream>>>(Aoutp, Wot, bo, (float*)d_out);
}